// Round 4
// baseline (132.984 us; speedup 1.0000x reference)
//
#include <hip/hip_runtime.h>
#include <math.h>

#define NCLS 81
#define A_ANCH 8732
#define B_BATCH 64
#define EPSF 1e-7f
#define NT 8732            // tiles of 64 flattened anchors: 64*8732 == 64 tiles * ... exact
#define TILE_DW (64 * NCLS)   // 5184 dwords per tile
#define GRID 768           // 3 blocks/CU * 256 CU

// ---------------- workspace layout ----------------
// [0]          neg_ce  : B*A floats
// [NEG_BYTES]  pos_loss: B floats
// [+256]       loc_loss: B floats
// [+512]       nm      : B ints
// [+768]       accum   : 2 doubles
// [+784]       hits    : 1 ull
static const size_t NEG_BYTES = (size_t)B_BATCH * A_ANCH * sizeof(float);

#define GLOAD_LDS16(g, l) __builtin_amdgcn_global_load_lds( \
    (const __attribute__((address_space(1))) void*)(g),      \
    (__attribute__((address_space(3))) void*)(l), 16, 0, 0)
#define GLOAD_LDS4(g, l) __builtin_amdgcn_global_load_lds(  \
    (const __attribute__((address_space(1))) void*)(g),      \
    (__attribute__((address_space(3))) void*)(l), 4, 0, 0)

// exactly 21 vmcnt ops per call: 20x width-16 + 1x width-4
__device__ __forceinline__ void stage_tile(const float* __restrict__ gsrc,
                                           float* lbase, int tid) {
    #pragma unroll
    for (int c = 0; c < 20; ++c) {
        GLOAD_LDS16(gsrc + c * 256 + tid * 4, lbase + c * 256);
    }
    GLOAD_LDS4(gsrc + 5120 + tid, lbase + 5120);
}

// ---------------- K1: per-anchor logsumexp + CE + GIoU ----------------
// Persistent single-wave blocks; double-buffered LDS; counted-vmcnt pipeline.
__global__ __launch_bounds__(64) void anchor_kernel(
    const float* __restrict__ conf, const float* __restrict__ loc,
    const float* __restrict__ tgt, float* __restrict__ neg_ce,
    float* __restrict__ pos_loss, float* __restrict__ loc_loss, int* __restrict__ nm)
{
    __shared__ float sconf[2][TILE_DW];   // 41,472 B -> 3 blocks/CU

    int tid = threadIdx.x;
    int t = blockIdx.x;
    if (t >= NT) return;

    stage_tile(conf + (size_t)t * TILE_DW, &sconf[0][0], tid);
    int par = 0;

    #pragma clang loop unroll(disable)
    while (true) {
        int tn = t + GRID;
        bool more = (tn < NT);
        if (more) stage_tile(conf + (size_t)tn * TILE_DW, &sconf[par ^ 1][0], tid);

        int idx = t * 64 + tid;                 // flattened anchor id, < 2^31
        int label = (int)tgt[(size_t)idx * 5 + 4];  // overlaps the wait

        // everything older than the 21 loads just issued is complete after this:
        if (more) { asm volatile("s_waitcnt vmcnt(16)" ::: "memory"); }
        else      { asm volatile("s_waitcnt vmcnt(0)"  ::: "memory"); }
        __builtin_amdgcn_sched_barrier(0);

        const float* r = &sconf[par][0] + tid * NCLS;  // stride-81: 2-way alias = free
        float s0 = 0.f, s1 = 0.f, s2 = 0.f, s3 = 0.f;
        #pragma unroll
        for (int j = 0; j < 80; j += 4) {
            s0 += __expf(r[j]);
            s1 += __expf(r[j + 1]);
            s2 += __expf(r[j + 2]);
            s3 += __expf(r[j + 3]);
        }
        float s   = (s0 + s1) + (s2 + s3) + __expf(r[80]);
        float lse = __logf(s);

        int b = idx / A_ANCH;                   // 32-bit magic-mul
        if (label > 0) {
            float ce = lse - r[label];
            float4 p = *(const float4*)(loc + (size_t)idx * 4);
            const float* tg = tgt + (size_t)idx * 5;
            float tx1 = tg[0], ty1 = tg[1], tx2 = tg[2], ty2 = tg[3];
            float area_p = (p.z - p.x) * (p.w - p.y);
            float area_t = (tx2 - tx1) * (ty2 - ty1);
            float iw = fmaxf(fminf(p.z, tx2) - fmaxf(p.x, tx1), 0.f);
            float ih = fmaxf(fminf(p.w, ty2) - fmaxf(p.y, ty1), 0.f);
            float inter = iw * ih;
            float uni   = area_p + area_t - inter;
            float iou   = inter / (uni + EPSF);
            float cw = fmaxf(p.z, tx2) - fminf(p.x, tx1);
            float ch = fmaxf(p.w, ty2) - fminf(p.y, ty1);
            float area_c = cw * ch;
            float giou = iou - (area_c - uni) / (area_c + EPSF);
            atomicAdd(&pos_loss[b], ce);
            atomicAdd(&loc_loss[b], 1.f - giou);
            atomicAdd(&nm[b], 1);
            neg_ce[idx] = -1.f;
        } else {
            neg_ce[idx] = lse - r[0];   // = -logp[0] > 0 always
        }

        if (!more) break;
        t = tn; par ^= 1;
    }
}

// ---------------- K2: per-batch top-k sum (hard negative mining) ----------------
#define K2_T 1024
#define VPT 9   // ceil(8732/1024)

__global__ __launch_bounds__(K2_T) void topk_kernel(
    const float* __restrict__ neg_ce, const float* __restrict__ pos_loss,
    const float* __restrict__ loc_loss, const int* __restrict__ nm,
    double* __restrict__ accum, unsigned long long* __restrict__ hits)
{
    __shared__ int   cnt[36];   // one pre-zeroed slot per binary-search iteration
    __shared__ float fsum[4];
    int b = blockIdx.x, tid = threadIdx.x;
    int lane = tid & 63;
    if (tid < 36) cnt[tid] = 0;
    if (tid < 4)  fsum[tid] = 0.f;

    float v[VPT];
    #pragma unroll
    for (int i = 0; i < VPT; ++i) {
        int idx = tid + i * K2_T;
        v[i] = (idx < A_ANCH) ? neg_ce[(size_t)b * A_ANCH + idx] : -1.f;
    }

    // count & sum of all non-negative entries (pos anchors marked -1)
    int c = 0; float s = 0.f;
    #pragma unroll
    for (int i = 0; i < VPT; ++i) { if (v[i] >= 0.f) { c++; s += v[i]; } }
    for (int off = 32; off; off >>= 1) { c += __shfl_xor(c, off); s += __shfl_xor(s, off); }
    __syncthreads();
    if (lane == 0) { atomicAdd(&cnt[32], c); atomicAdd(&fsum[0], s); }
    __syncthreads();
    int c0 = cnt[32]; float sall = fsum[0];
    int k = 3 * nm[b];

    float negl = 0.f;
    if (k >= c0) {
        negl = sall;
    } else if (k > 0) {
        // binary search on IEEE bits for the k-th largest value (values > 0)
        unsigned lo = 0u, hi = 0x7F800000u;
        int it = 0;
        while (hi - lo > 1u) {            // 31 uniform iterations
            unsigned mid = lo + (hi - lo) / 2u;
            float thr = __uint_as_float(mid);
            int cc = 0;
            #pragma unroll
            for (int i = 0; i < VPT; ++i) cc += (v[i] >= thr) ? 1 : 0;
            for (int off = 32; off; off >>= 1) cc += __shfl_xor(cc, off);
            if (lane == 0) atomicAdd(&cnt[it], cc);
            __syncthreads();
            if (cnt[it] >= k) lo = mid; else hi = mid;
            ++it;
        }
        float t = __uint_as_float(lo);    // exact k-th largest value
        int cg = 0; float sg = 0.f;
        #pragma unroll
        for (int i = 0; i < VPT; ++i) { if (v[i] > t) { cg++; sg += v[i]; } }
        for (int off = 32; off; off >>= 1) { cg += __shfl_xor(cg, off); sg += __shfl_xor(sg, off); }
        if (lane == 0) { atomicAdd(&cnt[33], cg); atomicAdd(&fsum[1], sg); }
        __syncthreads();
        negl = fsum[1] + (float)(k - cnt[33]) * t;   // ties contribute value t
    }

    if (tid == 0) {
        atomicAdd(&accum[0], (double)(pos_loss[b] + negl));
        atomicAdd(&accum[1], (double)loc_loss[b]);
        atomicAdd(hits, (unsigned long long)nm[b]);
    }
}

// ---------------- K3: finalize ----------------
__global__ void finalize_kernel(const double* __restrict__ accum,
                                const unsigned long long* __restrict__ hits,
                                float* __restrict__ out) {
    if (threadIdx.x == 0 && blockIdx.x == 0) {
        double conf_s = accum[0], loc_s = accum[1];
        unsigned long long h = *hits;
        double denom = (double)(h > 0 ? h : 1ull);
        if (h > 0) {
            out[0] = (float)((conf_s + loc_s) / denom);
            out[1] = (float)(conf_s / denom);
            out[2] = (float)(loc_s / denom);
        } else {
            out[0] = 0.f; out[1] = 0.f; out[2] = 0.f;
        }
    }
}

extern "C" void kernel_launch(void* const* d_in, const int* in_sizes, int n_in,
                              void* d_out, int out_size, void* d_ws, size_t ws_size,
                              hipStream_t stream) {
    const float* conf = (const float*)d_in[0];
    const float* loc  = (const float*)d_in[1];
    const float* tgt  = (const float*)d_in[2];
    float* out = (float*)d_out;

    char* ws = (char*)d_ws;
    float* neg_ce   = (float*)ws;
    float* pos_loss = (float*)(ws + NEG_BYTES);
    float* loc_loss = (float*)(ws + NEG_BYTES + 256);
    int*   nm       = (int*)  (ws + NEG_BYTES + 512);
    double* accum   = (double*)(ws + NEG_BYTES + 768);
    unsigned long long* hits = (unsigned long long*)(ws + NEG_BYTES + 784);

    // zero the small accumulator region (graph-capturable async memset)
    hipMemsetAsync(ws + NEG_BYTES, 0, 1024, stream);

    anchor_kernel<<<dim3(GRID), dim3(64), 0, stream>>>(
        conf, loc, tgt, neg_ce, pos_loss, loc_loss, nm);
    topk_kernel<<<dim3(B_BATCH), dim3(K2_T), 0, stream>>>(
        neg_ce, pos_loss, loc_loss, nm, accum, hits);
    finalize_kernel<<<1, 64, 0, stream>>>(accum, hits, out);
}

// Round 5
// 62.780 us; speedup vs baseline: 2.1183x; 2.1183x over previous
//
#include <hip/hip_runtime.h>
#include <math.h>

#define NCLS 81
#define A_ANCH 8732
#define B_BATCH 64
#define NANCH (B_BATCH * A_ANCH)   // 558,848 anchors
#define EPSF 1e-7f

// ---- K1 tiling: 32 anchors/tile, 2592 dwords, staged as 10x1KB + 1x256B ----
#define TILE 32
#define TDW  (TILE * NCLS)          // 2592 dwords
#define BUFDW 2816                  // 11*256: padded so the tail chunk lands in-buffer
#define NT2  (NANCH / TILE)         // 17,464 tiles (exact)
#define GRID1 1792                  // 7 blocks/CU * 256 CU

// ---------------- workspace layout ----------------
// [0]      sout : NANCH floats ( -logp0 per anchor; -1 written later is NOT needed --
//                                positives are masked in-register in K2 )
// [SBYTES] accum: 2 doubles (conf_sum, loc_sum)
// [+16]    hits : 1 ull
static const size_t SBYTES = (size_t)NANCH * sizeof(float);

#define GLOAD_LDS16(g, l) __builtin_amdgcn_global_load_lds( \
    (const __attribute__((address_space(1))) void*)(g),      \
    (__attribute__((address_space(3))) void*)(l), 16, 0, 0)
#define GLOAD_LDS4(g, l) __builtin_amdgcn_global_load_lds(  \
    (const __attribute__((address_space(1))) void*)(g),      \
    (__attribute__((address_space(3))) void*)(l), 4, 0, 0)

// exactly 11 vmem ops per call
__device__ __forceinline__ void stage_tile(const float* __restrict__ gsrc,
                                           float* lbase, int tid) {
    #pragma unroll
    for (int c = 0; c < 10; ++c) {
        GLOAD_LDS16(gsrc + c * 256 + tid * 4, lbase + c * 256);
    }
    // tail: 32 valid dwords; width-4 over all 64 lanes loads 64 dwords.
    // 128B global over-read (within allocation page) + LDS padding: harmless.
    GLOAD_LDS4(gsrc + 2560 + tid, lbase + 2560);
}

// ---------------- K1: streaming -logp0 (lse - x0) per anchor ----------------
// Single-wave persistent blocks, double-buffered LDS, exact counted-vmcnt
// pipeline: loop body issues EXACTLY 11 stage ops + 1 store -> vmcnt(11)
// guarantees tile t landed while tile t+1 stays fully in flight.
__global__ __launch_bounds__(64) void lse_kernel(
    const float* __restrict__ conf, float* __restrict__ sout,
    double* __restrict__ accum, unsigned long long* __restrict__ hits)
{
    __shared__ float sb[2][BUFDW];   // 22,528 B -> 7 blocks/CU

    int tid = threadIdx.x;
    if (blockIdx.x == 0 && tid == 0) {   // zero accumulators (K2 runs after K1)
        accum[0] = 0.0; accum[1] = 0.0; *hits = 0ull;
    }

    int t = blockIdx.x;
    stage_tile(conf + (size_t)t * TDW, &sb[0][0], tid);
    int par = 0;
    int a = tid & 31, h = tid >> 5;      // 2 lanes per anchor: h=0 -> cls 0..39, h=1 -> 40..80

    #pragma clang loop unroll(disable)
    while (true) {
        int tn = t + GRID1;
        bool more = (tn < NT2);
        if (more) stage_tile(conf + (size_t)tn * TDW, &sb[par ^ 1][0], tid);

        // in-order vmcnt retirement: <=11 outstanding => newest 11 (= tile t+1's
        // stage) may remain; tile t's stage and last iter's store are drained.
        if (more) { asm volatile("s_waitcnt vmcnt(11)" ::: "memory"); }
        else      { asm volatile("s_waitcnt vmcnt(0)"  ::: "memory"); }
        __builtin_amdgcn_sched_barrier(0);

        const float* r = &sb[par][a * 81 + h * 40];
        float x0 = r[0];                 // h=0: class 0 (the one we need)
        float s0 = 0.f, s1 = 0.f, s2 = 0.f, s3 = 0.f;
        #pragma unroll
        for (int j = 0; j < 40; j += 4) {
            s0 += __expf(r[j]);
            s1 += __expf(r[j + 1]);
            s2 += __expf(r[j + 2]);
            s3 += __expf(r[j + 3]);
        }
        float s = (s0 + s1) + (s2 + s3) + (float)h * __expf(r[40]);  // h=1 adds class 80
        s += __shfl_xor(s, 32);          // combine the two half-rows
        if (h == 0) sout[t * TILE + a] = __logf(s) - x0;   // = -logp0 > 0

        if (!more) break;
        t = tn; par ^= 1;
    }
}

// ---------------- K2: per-batch positives + hard-negative mining ----------------
#define K2_T 1024
#define VPT 9   // ceil(8732/1024)

__global__ __launch_bounds__(K2_T) void mine_kernel(
    const float* __restrict__ conf, const float* __restrict__ loc,
    const float* __restrict__ tgt, const float* __restrict__ sout,
    double* __restrict__ accum, unsigned long long* __restrict__ hits)
{
    __shared__ int   cnt[34];   // slots 0..30: bisect iters, 32: c0, 33: cg
    __shared__ float fs[4];     // 0: sall, 1: sg, 2: pos_ce, 3: pos_loc
    __shared__ int   nm_s;
    int b = blockIdx.x, tid = threadIdx.x, lane = tid & 63;
    if (tid < 34) cnt[tid] = 0;
    if (tid < 4)  fs[tid] = 0.f;
    if (tid == 0) nm_s = 0;
    __syncthreads();

    float v[VPT]; int lab[VPT];
    size_t base = (size_t)b * A_ANCH;
    #pragma unroll
    for (int i = 0; i < VPT; ++i) {
        int idx = tid + i * K2_T;
        bool in = idx < A_ANCH;
        v[i]   = in ? sout[base + idx] : -1.f;
        lab[i] = in ? (int)tgt[(base + idx) * 5 + 4] : 0;
    }

    // ---- positives: CE correction + GIoU; mask out of mining ----
    float pce = 0.f, ploc = 0.f; int pc = 0;
    #pragma unroll
    for (int i = 0; i < VPT; ++i) {
        if (lab[i] > 0) {
            size_t gi = base + (size_t)(tid + i * K2_T);
            float r0 = conf[gi * NCLS];
            float rl = conf[gi * NCLS + lab[i]];
            pce += v[i] + r0 - rl;       // ce = lse - r[label] = (lse-r0) + r0 - rl
            float4 p = *(const float4*)(loc + gi * 4);
            const float* tg = tgt + gi * 5;
            float tx1 = tg[0], ty1 = tg[1], tx2 = tg[2], ty2 = tg[3];
            float area_p = (p.z - p.x) * (p.w - p.y);
            float area_t = (tx2 - tx1) * (ty2 - ty1);
            float iw = fmaxf(fminf(p.z, tx2) - fmaxf(p.x, tx1), 0.f);
            float ih = fmaxf(fminf(p.w, ty2) - fmaxf(p.y, ty1), 0.f);
            float inter = iw * ih;
            float uni   = area_p + area_t - inter;
            float iou   = inter / (uni + EPSF);
            float cw = fmaxf(p.z, tx2) - fminf(p.x, tx1);
            float ch = fmaxf(p.w, ty2) - fminf(p.y, ty1);
            float area_c = cw * ch;
            ploc += 1.f - (iou - (area_c - uni) / (area_c + EPSF));
            pc++;
            v[i] = -1.f;                 // exclude from mining
        }
    }
    for (int off = 32; off; off >>= 1) {
        pc   += __shfl_xor(pc, off);
        pce  += __shfl_xor(pce, off);
        ploc += __shfl_xor(ploc, off);
    }
    if (lane == 0) {
        if (pc) atomicAdd(&nm_s, pc);
        atomicAdd(&fs[2], pce);
        atomicAdd(&fs[3], ploc);
    }

    // ---- count & sum of all mining candidates (v >= 0) ----
    int c = 0; float sa = 0.f;
    #pragma unroll
    for (int i = 0; i < VPT; ++i) { if (v[i] >= 0.f) { c++; sa += v[i]; } }
    for (int off = 32; off; off >>= 1) { c += __shfl_xor(c, off); sa += __shfl_xor(sa, off); }
    if (lane == 0) { atomicAdd(&cnt[32], c); atomicAdd(&fs[0], sa); }
    __syncthreads();

    int k = 3 * nm_s;
    int c0 = cnt[32]; float sall = fs[0];
    float negl = 0.f;
    if (k >= c0) {
        negl = sall;
    } else if (k > 0) {
        // bisect IEEE bits for the k-th largest candidate (values > 0)
        unsigned lo = 0u, hi = 0x7F800000u;
        int it = 0;
        while (hi - lo > 1u) {           // 31 uniform iterations
            unsigned mid = lo + (hi - lo) / 2u;
            float thr = __uint_as_float(mid);
            int cc = 0;
            #pragma unroll
            for (int i = 0; i < VPT; ++i) cc += (v[i] >= thr) ? 1 : 0;
            for (int off = 32; off; off >>= 1) cc += __shfl_xor(cc, off);
            if (lane == 0) atomicAdd(&cnt[it], cc);
            __syncthreads();
            if (cnt[it] >= k) lo = mid; else hi = mid;
            ++it;
        }
        float tth = __uint_as_float(lo); // exact k-th largest value
        int cg = 0; float sg = 0.f;
        #pragma unroll
        for (int i = 0; i < VPT; ++i) { if (v[i] > tth) { cg++; sg += v[i]; } }
        for (int off = 32; off; off >>= 1) { cg += __shfl_xor(cg, off); sg += __shfl_xor(sg, off); }
        if (lane == 0) { atomicAdd(&cnt[33], cg); atomicAdd(&fs[1], sg); }
        __syncthreads();
        negl = fs[1] + (float)(k - cnt[33]) * tth;   // ties contribute value tth
    }

    if (tid == 0) {
        atomicAdd(&accum[0], (double)(fs[2] + negl));
        atomicAdd(&accum[1], (double)fs[3]);
        atomicAdd(hits, (unsigned long long)nm_s);
    }
}

// ---------------- K3: finalize ----------------
__global__ void finalize_kernel(const double* __restrict__ accum,
                                const unsigned long long* __restrict__ hits,
                                float* __restrict__ out) {
    if (threadIdx.x == 0 && blockIdx.x == 0) {
        double conf_s = accum[0], loc_s = accum[1];
        unsigned long long h = *hits;
        double denom = (double)(h > 0 ? h : 1ull);
        if (h > 0) {
            out[0] = (float)((conf_s + loc_s) / denom);
            out[1] = (float)(conf_s / denom);
            out[2] = (float)(loc_s / denom);
        } else {
            out[0] = 0.f; out[1] = 0.f; out[2] = 0.f;
        }
    }
}

extern "C" void kernel_launch(void* const* d_in, const int* in_sizes, int n_in,
                              void* d_out, int out_size, void* d_ws, size_t ws_size,
                              hipStream_t stream) {
    const float* conf = (const float*)d_in[0];
    const float* loc  = (const float*)d_in[1];
    const float* tgt  = (const float*)d_in[2];
    float* out = (float*)d_out;

    char* ws = (char*)d_ws;
    float* sout = (float*)ws;
    double* accum = (double*)(ws + SBYTES);
    unsigned long long* hits = (unsigned long long*)(ws + SBYTES + 16);

    lse_kernel<<<dim3(GRID1), dim3(64), 0, stream>>>(conf, sout, accum, hits);
    mine_kernel<<<dim3(B_BATCH), dim3(K2_T), 0, stream>>>(
        conf, loc, tgt, sout, accum, hits);
    finalize_kernel<<<1, 64, 0, stream>>>(accum, hits, out);
}